// Round 4
// baseline (534.545 us; speedup 1.0000x reference)
//
#include <hip/hip_runtime.h>
#include <math.h>

typedef __bf16 bf16_t;
typedef __bf16 bf16x8 __attribute__((ext_vector_type(8)));
typedef float  f32x4  __attribute__((ext_vector_type(4)));

#define B_    16
#define CIN_  32
#define COUT_ 32
#define G_    8
#define CH_   256      // Cin*Gin = K channels per tap
#define H_    64
#define W_    64
#define HID_  32
#define KS_   7
#define PAD_  3
#define WP_   70       // W + 2*PAD

// xp layout: [B][y(70)][c16(32)][x(70)][8ch]  (chunk-major rows).
#define ROW_ELEMS  (WP_ * CH_)                                // 17,920 per row
#define XP_ELEMS   ((size_t)B_ * WP_ * ROW_ELEMS)             // 20,070,400
#define XP_BYTES   (XP_ELEMS * 2)                             // 40,140,800

#define GENW_BLOCKS   (G_ * KS_ * KS_)                        // 392 = (gout, tap)
#define REPACK_BLOCKS (B_ * (H_ + 6))                         // 1120
#define CONV_BLOCKS   (B_ * (H_ / 2))                         // 512 = 2/CU exactly

static __device__ __forceinline__ unsigned pack_bf16(float a, float b) {
    union { __bf16 h; unsigned short u; } ua, ub;
    ua.h = (__bf16)a; ub.h = (__bf16)b;
    return (unsigned)ua.u | ((unsigned)ub.u << 16);
}

static __device__ __forceinline__ void dma16(const bf16_t* g, bf16_t* l) {
    __builtin_amdgcn_global_load_lds(
        (const __attribute__((address_space(1))) void*)g,
        (__attribute__((address_space(3))) void*)l, 16, 0, 0);
}

// ---------------------------------------------------------------------------
// Fused prep.
//   blocks [0, 392): gen_w, block = (gout, tap p).  Lane map cout = o&31 so a
//     wave's 64 bf16x8 stores form two contiguous 512B runs (R0/R1 gen_w had
//     64 scattered lines per wave-store -> suspect for the ~140us prep gap
//     above memory floor).  One 16B store per (cout,cin), all 8 gin inside.
//   blocks [392, 1512): repack x -> chunk-major bf16 xPad (unchanged).
__global__ void prep(const float* __restrict__ x, bf16_t* __restrict__ xp,
                     const float* __restrict__ thetas,
                     const float* __restrict__ W1, const float* __restrict__ b1,
                     const float* __restrict__ W2, const float* __restrict__ b2,
                     const float* __restrict__ W3, const float* __restrict__ b3,
                     bf16_t* __restrict__ w2out) {
    __shared__ float h1s[8][33];
    __shared__ float h2s[8][33];
    int tid = threadIdx.x;
    if (blockIdx.x < GENW_BLOCKS) {
        // ---------------- gen_w path: block = (gout, tap p) ----------------
        int blk = blockIdx.x;
        int gout = blk / 49, p = blk - gout * 49;
        int ky = p / 7, kx = p - ky * 7;
        const float TWO_PI = 6.283185307179586f;
        const float PI_F   = 3.14159265358979323846f;
        float th_o = thetas[gout];
        float ct = cosf(-th_o), st = sinf(-th_o);
        float yy = (float)(ky - 3) / 3.0f;
        float xx = (float)(kx - 3) / 3.0f;
        float r0 = ct * yy - st * xx;
        float r1 = st * yy + ct * xx;
        // radius-1 points INCLUDED (fp32 ref)
        float maskv = (r0 * r0 + r1 * r1 <= 1.00001f) ? 1.0f : 0.0f;

        int gin = tid >> 5, j = tid & 31;
        {
            float th_i = thetas[gin];
            float d = fmodf(th_i - th_o, TWO_PI);
            if (d < 0.0f) d += TWO_PI;
            float ag = d / PI_F - 1.0f;
            float a = r0 * W1[j] + r1 * W1[32 + j] + ag * W1[64 + j] + b1[j];
            h1s[gin][j] = __sinf(10.0f * a);
        }
        __syncthreads();
        {
            float a = b2[j];
            #pragma unroll
            for (int i = 0; i < HID_; ++i) a += h1s[gin][i] * W2[i * HID_ + j];
            h2s[gin][j] = __sinf(10.0f * a);
        }
        __syncthreads();
        #pragma unroll 1
        for (int rep = 0; rep < 4; ++rep) {
            int o = rep * 256 + tid;
            int cout = o & 31, cin = o >> 5;      // cout innermost -> coalesced stores
            int col = cout * 32 + cin;            // W3 column index (cout*Cin + cin)
            float w3c[HID_];
            #pragma unroll
            for (int i = 0; i < HID_; ++i) w3c[i] = W3[i * 1024 + col];
            float bb = b3[col];
            union { bf16x8 v; bf16_t e[8]; } o8;
            #pragma unroll
            for (int g = 0; g < 8; ++g) {         // k = cin*8+g -> addr = cin*2048 + n*8 + g
                float a = bb;
                #pragma unroll
                for (int i = 0; i < HID_; ++i) a += h2s[g][i] * w3c[i];
                o8.e[g] = (bf16_t)(a * maskv);
            }
            size_t base = (size_t)p * 65536 + (size_t)cin * 2048
                        + (size_t)(gout * COUT_ + cout) * 8;
            *reinterpret_cast<bf16x8*>(w2out + base) = o8.v;
        }
        return;
    }
    // ---------------- repack path ----------------
    int blk = blockIdx.x - GENW_BLOCKS;
    int b = blk / (H_ + 6), hy = blk % (H_ + 6);
    const int4 z4 = make_int4(0, 0, 0, 0);
    if (hy >= H_) {
        int idx = hy - H_;
        int y = (idx < 3) ? idx : idx + 64;   // 0,1,2,67,68,69
        bf16_t* dst = xp + ((size_t)(b * WP_) + y) * ROW_ELEMS;
        for (int i = tid; i < ROW_ELEMS / 8; i += 256)
            *reinterpret_cast<int4*>(dst + (size_t)i * 8) = z4;
        return;
    }
    int lane = tid & 63, wv = tid >> 6;
    int r = lane >> 3;          // channel offset in tile -> w offset after T
    int t = lane & 7;           // w-chunk
    size_t orow = ((size_t)(b * WP_) + (hy + 3)) * ROW_ELEMS;
    for (int it = 0; it < 8; ++it) {
        int c0 = wv * 8 + it * 32;
        const float* src = x + ((size_t)(b * CH_ + c0 + r)) * (H_ * W_)
                             + (size_t)hy * W_ + t * 8;
        float4 f0 = *reinterpret_cast<const float4*>(src);
        float4 f1 = *reinterpret_cast<const float4*>(src + 4);
        int d0 = (int)pack_bf16(f0.x, f0.y);
        int d1 = (int)pack_bf16(f0.z, f0.w);
        int d2 = (int)pack_bf16(f1.x, f1.y);
        int d3 = (int)pack_bf16(f1.z, f1.w);
        int p0, p1, p2, p3;
        p0 = __shfl_xor(d0, 32); p1 = __shfl_xor(d1, 32);
        p2 = __shfl_xor(d2, 32); p3 = __shfl_xor(d3, 32);
        if ((r & 4) == 0) { d2 = p0; d3 = p1; } else { d0 = p2; d1 = p3; }
        p0 = __shfl_xor(d0, 16); p1 = __shfl_xor(d1, 16);
        p2 = __shfl_xor(d2, 16); p3 = __shfl_xor(d3, 16);
        if ((r & 2) == 0) { d1 = p0; d3 = p2; } else { d0 = p1; d2 = p3; }
        p0 = __shfl_xor(d0, 8); p1 = __shfl_xor(d1, 8);
        p2 = __shfl_xor(d2, 8); p3 = __shfl_xor(d3, 8);
        if ((r & 1) == 0) {
            d0 = (d0 & 0xFFFF) | (p0 << 16);
            d1 = (d1 & 0xFFFF) | (p1 << 16);
            d2 = (d2 & 0xFFFF) | (p2 << 16);
            d3 = (d3 & 0xFFFF) | (p3 << 16);
        } else {
            d0 = (d0 & 0xFFFF0000) | ((unsigned)p0 >> 16);
            d1 = (d1 & 0xFFFF0000) | ((unsigned)p1 >> 16);
            d2 = (d2 & 0xFFFF0000) | ((unsigned)p2 >> 16);
            d3 = (d3 & 0xFFFF0000) | ((unsigned)p3 >> 16);
        }
        int xpos = t * 8 + r + 3;
        int c16 = c0 >> 3;
        int4 v = make_int4(d0, d1, d2, d3);
        // chunk-major: wave's 64 stores cover one contiguous 1024B run
        *reinterpret_cast<int4*>(xp + orow + ((size_t)c16 * WP_ + xpos) * 8) = v;
    }
    if (tid < 192) {   // zero w-border cols {0,1,2,67,68,69} in every chunk
        int col = tid >> 5, cg = tid & 31;
        int xx = (col < 3) ? col : col + 64;
        *reinterpret_cast<int4*>(xp + orow + ((size_t)cg * WP_ + xx) * 8) = z4;
    }
}

// ---------------------------------------------------------------------------
// Conv: implicit GEMM, block = (b, h-pair), R2 wave layout (wave = 64-wide
// N-strip, full M=128, acc[8][4]) — best measured config (302us, MfmaUtil 65).
//
// R4 change (preamble elimination): the kc-octet is hand-unrolled so every
// ds_read offset and B-load offset is a compile-time immediate off a per-kx
// base.  w2's tap-space is linear in the flat step index, so the B pointer is
// a uniform (SGPR) base + loop-invariant lane offset -> no per-step 64-bit
// VGPR address arith (R3 counters: VALUBusy 21% ~ 100 VALU/step of pure
// addressing; 2 barrier-phase-locked waves/SIMD collide in these preambles
// and the matrix pipe idles 35%).  s_setprio(1) wraps each 32-MFMA cluster
// (T5) so the MFMA-ready wave wins arbitration during the other's preamble.
//
// CONV_STEP computes with AC/BC (prefetched last step) and prefetches step
// PC from uniform pointer PB (+AOF elems for the A next-kx case) into AN/BN.
#define CONV_STEP(AC, AN, BC, BN, PC, PB, AOF)                                \
  do {                                                                        \
    _Pragma("unroll")                                                         \
    for (int nt = 0; nt < 4; ++nt)                                            \
      BN[nt] = *reinterpret_cast<const bf16x8*>(                              \
          (PB) + wlane_off + (PC) * 8192 + nt * 128);                         \
    _Pragma("unroll")                                                         \
    for (int mt = 0; mt < 4; ++mt) {                                          \
      AN[mt]     = *reinterpret_cast<const bf16x8*>(                          \
          aA + ((PC) * 4 * WP_ + mt * 16) * 8 + (AOF));                       \
      AN[mt + 4] = *reinterpret_cast<const bf16x8*>(                          \
          aB + ((PC) * 4 * WP_ + mt * 16) * 8 + (AOF));                       \
    }                                                                         \
    __builtin_amdgcn_s_setprio(1);                                            \
    _Pragma("unroll")                                                         \
    for (int mt = 0; mt < 8; ++mt)                                            \
      _Pragma("unroll")                                                       \
      for (int nt = 0; nt < 4; ++nt)                                          \
        acc[mt][nt] = __builtin_amdgcn_mfma_f32_16x16x32_bf16(                \
            AC[mt], BC[nt], acc[mt][nt], 0, 0, 0);                            \
    __builtin_amdgcn_s_setprio(0);                                            \
  } while (0)

__launch_bounds__(256, 2)
__global__ void conv_mfma(const bf16_t* __restrict__ xp,
                          const bf16_t* __restrict__ w2,
                          const float* __restrict__ bias,
                          float* __restrict__ out) {
    __shared__ __align__(16) bf16_t lds[2][ROW_ELEMS];   // 71,680 B
    int blk = blockIdx.x;             // b*32 + hpair
    int b = blk >> 5, h0 = (blk & 31) << 1;
    int tid = threadIdx.x;
    int ns = tid >> 6, lane = tid & 63;
    int lm = lane & 15, lq = lane >> 4;
    int wlane_off = lq * 2048 + (ns * 64 + lm) * 8;   // divergent, loop-invariant

    f32x4 acc[8][4];
    #pragma unroll
    for (int i = 0; i < 8; ++i)
        #pragma unroll
        for (int j = 0; j < 4; ++j) {
            f32x4 z = {0.0f, 0.0f, 0.0f, 0.0f};
            acc[i][j] = z;
        }

    const bf16_t* rows = xp + (((size_t)(b * WP_) + h0)) * ROW_ELEMS;
    // init: stage rows h0 (slot0) and h0+1 (slot1): 70 chunks of 1KB, linear
    for (int c = ns; c < 70; c += 4)
        dma16(rows + (size_t)c * 512 + lane * 8, &lds[0][0] + c * 512);

    // B prologue: prefetch step (tap 0, kc 0)
    bf16x8 bcur[4], bnxt[4];
    #pragma unroll
    for (int nt = 0; nt < 4; ++nt)
        bcur[nt] = *reinterpret_cast<const bf16x8*>(w2 + wlane_off + nt * 128);
    __syncthreads();   // drains init DMA (vmcnt 0) before LDS reads

    for (int ky = 0; ky < KS_; ++ky) {
        const bf16_t* slotA = &lds[ky & 1][0];        // image row h0+ky   (mt 0-3)
        const bf16_t* slotB = &lds[(ky + 1) & 1][0];  // image row h0+ky+1 (mt 4-7)
        // A(0) prologue for this ky (kx=0, kc=0)
        bf16x8 acur[8], anxt[8];
        #pragma unroll
        for (int mt = 0; mt < 4; ++mt) {
            int xr = (lq * WP_ + lm) * 8 + mt * 128;
            acur[mt]     = *reinterpret_cast<const bf16x8*>(&slotA[xr]);
            acur[mt + 4] = *reinterpret_cast<const bf16x8*>(&slotB[xr]);
        }
        #pragma unroll 1
        for (int kx = 0; kx < 7; ++kx) {
            const bf16_t* wkx = w2 + (size_t)(ky * 7 + kx) * 65536;  // uniform
            const bf16_t* wnx = (ky == 6 && kx == 6) ? wkx : wkx + 65536;
            const bf16_t* aA = slotA + (lq * WP_ + lm + kx) * 8;
            const bf16_t* aB = slotB + (lq * WP_ + lm + kx) * 8;
            CONV_STEP(acur, anxt, bcur, bnxt, 1, wkx, 0);
            CONV_STEP(anxt, acur, bnxt, bcur, 2, wkx, 0);
            CONV_STEP(acur, anxt, bcur, bnxt, 3, wkx, 0);
            CONV_STEP(anxt, acur, bnxt, bcur, 4, wkx, 0);
            CONV_STEP(acur, anxt, bcur, bnxt, 5, wkx, 0);
            CONV_STEP(anxt, acur, bnxt, bcur, 6, wkx, 0);
            CONV_STEP(acur, anxt, bcur, bnxt, 7, wkx, 0);
            CONV_STEP(anxt, acur, bnxt, bcur, 0, wnx, 8);  // next kx / next ky B(0); A dead at kx=6
        }
        if (ky < KS_ - 1) {
            __syncthreads();   // all waves done with row h0+ky (slot ky&1)
            bf16_t* dstslot = &lds[ky & 1][0];
            const bf16_t* src = rows + (size_t)(ky + 2) * ROW_ELEMS;
            for (int c = ns; c < 35; c += 4)
                dma16(src + (size_t)c * 512 + lane * 8, dstslot + c * 512);
            __syncthreads();   // drain DMA
        }
    }

    // epilogue: D row = lq*4 + reg (w offset), col = lm (n offset)
    #pragma unroll
    for (int mt = 0; mt < 8; ++mt) {
        int h = h0 + (mt >> 2);
        int wq = (mt & 3) * 16 + lq * 4;
        #pragma unroll
        for (int nt = 0; nt < 4; ++nt) {
            int n = ns * 64 + nt * 16 + lm;
            int gout = n >> 5, cout = n & 31;
            float bv = bias[cout];
            f32x4 v = acc[mt][nt];
            v[0] += bv; v[1] += bv; v[2] += bv; v[3] += bv;
            float* po = out + (((size_t)(b * COUT_ + cout) * G_ + gout) * (H_ * W_)
                               + h * W_ + wq);
            *reinterpret_cast<f32x4*>(po) = v;
        }
    }
}

// ---------------------------------------------------------------------------
extern "C" void kernel_launch(void* const* d_in, const int* in_sizes, int n_in,
                              void* d_out, int out_size, void* d_ws, size_t ws_size,
                              hipStream_t stream) {
    const float* x      = (const float*)d_in[0];
    const float* thetas = (const float*)d_in[1];
    const float* W1     = (const float*)d_in[2];
    const float* b1     = (const float*)d_in[3];
    const float* W2     = (const float*)d_in[4];
    const float* b2     = (const float*)d_in[5];
    const float* W3     = (const float*)d_in[6];
    const float* b3     = (const float*)d_in[7];
    const float* bias   = (const float*)d_in[8];
    float* out = (float*)d_out;

    bf16_t* xp = (bf16_t*)d_ws;
    bf16_t* w2 = (bf16_t*)((char*)d_ws + XP_BYTES);

    hipLaunchKernelGGL(prep, dim3(GENW_BLOCKS + REPACK_BLOCKS), dim3(256), 0, stream,
                       x, xp, thetas, W1, b1, W2, b2, W3, b3, w2);
    hipLaunchKernelGGL(conv_mfma, dim3(CONV_BLOCKS), dim3(256), 0, stream,
                       xp, w2, bias, out);
}

// Round 5
// 447.978 us; speedup vs baseline: 1.1932x; 1.1932x over previous
//
#include <hip/hip_runtime.h>
#include <math.h>

typedef __bf16 bf16_t;
typedef __bf16 bf16x8 __attribute__((ext_vector_type(8)));
typedef float  f32x4  __attribute__((ext_vector_type(4)));

#define B_    16
#define CIN_  32
#define COUT_ 32
#define G_    8
#define CH_   256      // Cin*Gin = K channels per tap
#define H_    64
#define W_    64
#define HID_  32
#define KS_   7
#define PAD_  3
#define WP_   70       // W + 2*PAD

// xp layout: [B][y(70)][c16(32)][x(70)][8ch]  (chunk-major rows).
#define ROW_ELEMS  (WP_ * CH_)                                // 17,920 per row
#define XP_ELEMS   ((size_t)B_ * WP_ * ROW_ELEMS)             // 20,070,400
#define XP_BYTES   (XP_ELEMS * 2)                             // 40,140,800

#define REPACK_BLOCKS (B_ * (H_ + 6))                         // 1120
#define GENW_BLOCKS   (G_ * G_)                               // 64
#define CONV_BLOCKS   (B_ * (H_ / 2))                         // 512 = 2/CU exactly

static __device__ __forceinline__ unsigned pack_bf16(float a, float b) {
    union { __bf16 h; unsigned short u; } ua, ub;
    ua.h = (__bf16)a; ub.h = (__bf16)b;
    return (unsigned)ua.u | ((unsigned)ub.u << 16);
}

static __device__ __forceinline__ void dma16(const bf16_t* g, bf16_t* l) {
    __builtin_amdgcn_global_load_lds(
        (const __attribute__((address_space(1))) void*)g,
        (__attribute__((address_space(3))) void*)l, 16, 0, 0);
}

// ---------------------------------------------------------------------------
// Fused prep — EXACT R0 version (empirically fastest, 2x measured ~165us
// prep+gap vs 234/265us for the (gout,tap)-re-blocked variants).  Keep:
//   * repack blocks FIRST, gen_w blocks LAST (w2 written immediately before
//     conv consumes it -> stays warm; R4's gen_w-first raised conv FETCH
//     97->119MB);
//   * gen_w block = (gout,gin), W3 register reuse across all 49 taps.
// Do NOT re-block gen_w again without isolating prep first (R1+R4 lesson).
__global__ void prep(const float* __restrict__ x, bf16_t* __restrict__ xp,
                     const float* __restrict__ thetas,
                     const float* __restrict__ W1, const float* __restrict__ b1,
                     const float* __restrict__ W2, const float* __restrict__ b2,
                     const float* __restrict__ W3, const float* __restrict__ b3,
                     bf16_t* __restrict__ w2out) {
    __shared__ float h1s[49][33];
    __shared__ float h2s[49][33];
    __shared__ float masks[49];
    int tid = threadIdx.x;
    if (blockIdx.x < REPACK_BLOCKS) {
        // ---------------- repack path ----------------
        int blk = blockIdx.x;
        int b = blk / (H_ + 6), hy = blk % (H_ + 6);
        const int4 z4 = make_int4(0, 0, 0, 0);
        if (hy >= H_) {
            int idx = hy - H_;
            int y = (idx < 3) ? idx : idx + 64;   // 0,1,2,67,68,69
            bf16_t* dst = xp + ((size_t)(b * WP_) + y) * ROW_ELEMS;
            for (int i = tid; i < ROW_ELEMS / 8; i += 256)
                *reinterpret_cast<int4*>(dst + (size_t)i * 8) = z4;
            return;
        }
        int lane = tid & 63, wv = tid >> 6;
        int r = lane >> 3;          // channel offset in tile -> w offset after T
        int t = lane & 7;           // w-chunk
        size_t orow = ((size_t)(b * WP_) + (hy + 3)) * ROW_ELEMS;
        for (int it = 0; it < 8; ++it) {
            int c0 = wv * 8 + it * 32;
            const float* src = x + ((size_t)(b * CH_ + c0 + r)) * (H_ * W_)
                                 + (size_t)hy * W_ + t * 8;
            float4 f0 = *reinterpret_cast<const float4*>(src);
            float4 f1 = *reinterpret_cast<const float4*>(src + 4);
            int d0 = (int)pack_bf16(f0.x, f0.y);
            int d1 = (int)pack_bf16(f0.z, f0.w);
            int d2 = (int)pack_bf16(f1.x, f1.y);
            int d3 = (int)pack_bf16(f1.z, f1.w);
            int p0, p1, p2, p3;
            p0 = __shfl_xor(d0, 32); p1 = __shfl_xor(d1, 32);
            p2 = __shfl_xor(d2, 32); p3 = __shfl_xor(d3, 32);
            if ((r & 4) == 0) { d2 = p0; d3 = p1; } else { d0 = p2; d1 = p3; }
            p0 = __shfl_xor(d0, 16); p1 = __shfl_xor(d1, 16);
            p2 = __shfl_xor(d2, 16); p3 = __shfl_xor(d3, 16);
            if ((r & 2) == 0) { d1 = p0; d3 = p2; } else { d0 = p1; d2 = p3; }
            p0 = __shfl_xor(d0, 8); p1 = __shfl_xor(d1, 8);
            p2 = __shfl_xor(d2, 8); p3 = __shfl_xor(d3, 8);
            if ((r & 1) == 0) {
                d0 = (d0 & 0xFFFF) | (p0 << 16);
                d1 = (d1 & 0xFFFF) | (p1 << 16);
                d2 = (d2 & 0xFFFF) | (p2 << 16);
                d3 = (d3 & 0xFFFF) | (p3 << 16);
            } else {
                d0 = (d0 & 0xFFFF0000) | ((unsigned)p0 >> 16);
                d1 = (d1 & 0xFFFF0000) | ((unsigned)p1 >> 16);
                d2 = (d2 & 0xFFFF0000) | ((unsigned)p2 >> 16);
                d3 = (d3 & 0xFFFF0000) | ((unsigned)p3 >> 16);
            }
            int xpos = t * 8 + r + 3;
            int c16 = c0 >> 3;
            int4 v = make_int4(d0, d1, d2, d3);
            // chunk-major: wave's 64 stores cover one contiguous 1024B run
            *reinterpret_cast<int4*>(xp + orow + ((size_t)c16 * WP_ + xpos) * 8) = v;
        }
        if (tid < 192) {   // zero w-border cols {0,1,2,67,68,69} in every chunk
            int col = tid >> 5, cg = tid & 31;
            int xx = (col < 3) ? col : col + 64;
            *reinterpret_cast<int4*>(xp + orow + ((size_t)cg * WP_ + xx) * 8) = z4;
        }
        return;
    }
    // ---------------- gen_w path: block = (gout, gin) ----------------
    int blk = blockIdx.x - REPACK_BLOCKS;
    int gin = blk & 7, gout = blk >> 3;
    const float TWO_PI = 6.283185307179586f;
    const float PI_F   = 3.14159265358979323846f;
    float th_o = thetas[gout], th_i = thetas[gin];
    float d = fmodf(th_i - th_o, TWO_PI);
    if (d < 0.0f) d += TWO_PI;
    float ag = d / PI_F - 1.0f;
    float ct = cosf(-th_o), st = sinf(-th_o);

    if (tid < 196) {
        int p = tid >> 2, q = tid & 3;       // tap, j-octet
        int ky = p / 7, kx = p % 7;
        float yy = (float)(ky - 3) / 3.0f;
        float xx = (float)(kx - 3) / 3.0f;
        float r0 = ct * yy - st * xx;
        float r1 = st * yy + ct * xx;
        if (q == 0)   // radius-1 points INCLUDED (fp32 ref); next r^2 = 10/9
            masks[p] = (r0 * r0 + r1 * r1 <= 1.00001f) ? 1.0f : 0.0f;
        #pragma unroll
        for (int jo = 0; jo < 8; ++jo) {
            int j = q * 8 + jo;
            float a = r0 * W1[j] + r1 * W1[32 + j] + ag * W1[64 + j] + b1[j];
            h1s[p][j] = __sinf(10.0f * a);
        }
    }
    __syncthreads();
    if (tid < 196) {
        int p = tid >> 2, q = tid & 3;
        #pragma unroll
        for (int jo = 0; jo < 8; ++jo) {
            int j = q * 8 + jo;
            float a = b2[j];
            #pragma unroll
            for (int i = 0; i < HID_; ++i) a += h1s[p][i] * W2[i * HID_ + j];
            h2s[p][j] = __sinf(10.0f * a);
        }
    }
    __syncthreads();
    for (int rep = 0; rep < 4; ++rep) {
        int o = rep * 256 + tid;             // cout*32 + cin
        float w3c[HID_];
        #pragma unroll
        for (int i = 0; i < HID_; ++i) w3c[i] = W3[i * 1024 + o];
        float bb = b3[o];
        int cout = o >> 5, cin = o & 31;
        int k = cin * G_ + gin;
        int n = gout * COUT_ + cout;
        int kc = k >> 5, hi = (k >> 3) & 3, jj = k & 7;
        bf16_t* dst = w2out + (((size_t)kc * 4 + hi) * 256 + n) * 8 + jj;
        for (int p = 0; p < 49; ++p) {
            float a = bb;
            #pragma unroll
            for (int i = 0; i < HID_; ++i) a += h2s[p][i] * w3c[i];
            a *= masks[p];
            dst[(size_t)p * (8 * 4 * 256 * 8)] = (bf16_t)a;
        }
    }
}

// ---------------------------------------------------------------------------
// Conv — EXACT R4 version (269us, MfmaUtil 74.4).  Implicit GEMM, block =
// (b, h-pair), wave = 64-wide N-strip covering full M=128, acc[8][4].
// kc-octet hand-unrolled: every ds_read / B-load offset is a compile-time
// immediate off a per-kx base; B pointer is uniform SGPR base + loop-
// invariant lane offset (no per-step VGPR address arith).  s_setprio(1)
// around each 32-MFMA cluster (T5).  Both operand streams pipelined one
// step ahead (cur/nxt register rotation, compile-time indices only).
#define CONV_STEP(AC, AN, BC, BN, PC, PB, AOF)                                \
  do {                                                                        \
    _Pragma("unroll")                                                         \
    for (int nt = 0; nt < 4; ++nt)                                            \
      BN[nt] = *reinterpret_cast<const bf16x8*>(                              \
          (PB) + wlane_off + (PC) * 8192 + nt * 128);                         \
    _Pragma("unroll")                                                         \
    for (int mt = 0; mt < 4; ++mt) {                                          \
      AN[mt]     = *reinterpret_cast<const bf16x8*>(                          \
          aA + ((PC) * 4 * WP_ + mt * 16) * 8 + (AOF));                       \
      AN[mt + 4] = *reinterpret_cast<const bf16x8*>(                          \
          aB + ((PC) * 4 * WP_ + mt * 16) * 8 + (AOF));                       \
    }                                                                         \
    __builtin_amdgcn_s_setprio(1);                                            \
    _Pragma("unroll")                                                         \
    for (int mt = 0; mt < 8; ++mt)                                            \
      _Pragma("unroll")                                                       \
      for (int nt = 0; nt < 4; ++nt)                                          \
        acc[mt][nt] = __builtin_amdgcn_mfma_f32_16x16x32_bf16(                \
            AC[mt], BC[nt], acc[mt][nt], 0, 0, 0);                            \
    __builtin_amdgcn_s_setprio(0);                                            \
  } while (0)

__launch_bounds__(256, 2)
__global__ void conv_mfma(const bf16_t* __restrict__ xp,
                          const bf16_t* __restrict__ w2,
                          const float* __restrict__ bias,
                          float* __restrict__ out) {
    __shared__ __align__(16) bf16_t lds[2][ROW_ELEMS];   // 71,680 B
    int blk = blockIdx.x;             // b*32 + hpair
    int b = blk >> 5, h0 = (blk & 31) << 1;
    int tid = threadIdx.x;
    int ns = tid >> 6, lane = tid & 63;
    int lm = lane & 15, lq = lane >> 4;
    int wlane_off = lq * 2048 + (ns * 64 + lm) * 8;   // divergent, loop-invariant

    f32x4 acc[8][4];
    #pragma unroll
    for (int i = 0; i < 8; ++i)
        #pragma unroll
        for (int j = 0; j < 4; ++j) {
            f32x4 z = {0.0f, 0.0f, 0.0f, 0.0f};
            acc[i][j] = z;
        }

    const bf16_t* rows = xp + (((size_t)(b * WP_) + h0)) * ROW_ELEMS;
    // init: stage rows h0 (slot0) and h0+1 (slot1): 70 chunks of 1KB, linear
    for (int c = ns; c < 70; c += 4)
        dma16(rows + (size_t)c * 512 + lane * 8, &lds[0][0] + c * 512);

    // B prologue: prefetch step (tap 0, kc 0)
    bf16x8 bcur[4], bnxt[4];
    #pragma unroll
    for (int nt = 0; nt < 4; ++nt)
        bcur[nt] = *reinterpret_cast<const bf16x8*>(w2 + wlane_off + nt * 128);
    __syncthreads();   // drains init DMA (vmcnt 0) before LDS reads

    for (int ky = 0; ky < KS_; ++ky) {
        const bf16_t* slotA = &lds[ky & 1][0];        // image row h0+ky   (mt 0-3)
        const bf16_t* slotB = &lds[(ky + 1) & 1][0];  // image row h0+ky+1 (mt 4-7)
        // A(0) prologue for this ky (kx=0, kc=0)
        bf16x8 acur[8], anxt[8];
        #pragma unroll
        for (int mt = 0; mt < 4; ++mt) {
            int xr = (lq * WP_ + lm) * 8 + mt * 128;
            acur[mt]     = *reinterpret_cast<const bf16x8*>(&slotA[xr]);
            acur[mt + 4] = *reinterpret_cast<const bf16x8*>(&slotB[xr]);
        }
        #pragma unroll 1
        for (int kx = 0; kx < 7; ++kx) {
            const bf16_t* wkx = w2 + (size_t)(ky * 7 + kx) * 65536;  // uniform
            const bf16_t* wnx = (ky == 6 && kx == 6) ? wkx : wkx + 65536;
            const bf16_t* aA = slotA + (lq * WP_ + lm + kx) * 8;
            const bf16_t* aB = slotB + (lq * WP_ + lm + kx) * 8;
            CONV_STEP(acur, anxt, bcur, bnxt, 1, wkx, 0);
            CONV_STEP(anxt, acur, bnxt, bcur, 2, wkx, 0);
            CONV_STEP(acur, anxt, bcur, bnxt, 3, wkx, 0);
            CONV_STEP(anxt, acur, bnxt, bcur, 4, wkx, 0);
            CONV_STEP(acur, anxt, bcur, bnxt, 5, wkx, 0);
            CONV_STEP(anxt, acur, bnxt, bcur, 6, wkx, 0);
            CONV_STEP(acur, anxt, bcur, bnxt, 7, wkx, 0);
            CONV_STEP(anxt, acur, bnxt, bcur, 0, wnx, 8);  // next kx / next ky B(0); A dead at kx=6
        }
        if (ky < KS_ - 1) {
            __syncthreads();   // all waves done with row h0+ky (slot ky&1)
            bf16_t* dstslot = &lds[ky & 1][0];
            const bf16_t* src = rows + (size_t)(ky + 2) * ROW_ELEMS;
            for (int c = ns; c < 35; c += 4)
                dma16(src + (size_t)c * 512 + lane * 8, dstslot + c * 512);
            __syncthreads();   // drain DMA
        }
    }

    // epilogue: D row = lq*4 + reg (w offset), col = lm (n offset)
    #pragma unroll
    for (int mt = 0; mt < 8; ++mt) {
        int h = h0 + (mt >> 2);
        int wq = (mt & 3) * 16 + lq * 4;
        #pragma unroll
        for (int nt = 0; nt < 4; ++nt) {
            int n = ns * 64 + nt * 16 + lm;
            int gout = n >> 5, cout = n & 31;
            float bv = bias[cout];
            f32x4 v = acc[mt][nt];
            v[0] += bv; v[1] += bv; v[2] += bv; v[3] += bv;
            float* po = out + (((size_t)(b * COUT_ + cout) * G_ + gout) * (H_ * W_)
                               + h * W_ + wq);
            *reinterpret_cast<f32x4*>(po) = v;
        }
    }
}

// ---------------------------------------------------------------------------
extern "C" void kernel_launch(void* const* d_in, const int* in_sizes, int n_in,
                              void* d_out, int out_size, void* d_ws, size_t ws_size,
                              hipStream_t stream) {
    const float* x      = (const float*)d_in[0];
    const float* thetas = (const float*)d_in[1];
    const float* W1     = (const float*)d_in[2];
    const float* b1     = (const float*)d_in[3];
    const float* W2     = (const float*)d_in[4];
    const float* b2     = (const float*)d_in[5];
    const float* W3     = (const float*)d_in[6];
    const float* b3     = (const float*)d_in[7];
    const float* bias   = (const float*)d_in[8];
    float* out = (float*)d_out;

    bf16_t* xp = (bf16_t*)d_ws;
    bf16_t* w2 = (bf16_t*)((char*)d_ws + XP_BYTES);

    hipLaunchKernelGGL(prep, dim3(REPACK_BLOCKS + GENW_BLOCKS), dim3(256), 0, stream,
                       x, xp, thetas, W1, b1, W2, b2, W3, b3, w2);
    hipLaunchKernelGGL(conv_mfma, dim3(CONV_BLOCKS), dim3(256), 0, stream,
                       xp, w2, bias, out);
}